// Round 12
// baseline (42.701 us; speedup 1.0000x reference)
//
#include <hip/hip_runtime.h>

#define NB 131072
#define NSTEPS 30
// 0.8^30 and 1-0.8^30
#define LAMBDA  1.2379400392853803e-3f
#define ONEMLAM 0.9987620599607146f

typedef float  float4v __attribute__((ext_vector_type(4)));
typedef short  short4v __attribute__((ext_vector_type(4)));

#define MFMA16 __builtin_amdgcn_mfma_f32_16x16x16bf16_1k

static __device__ __forceinline__ unsigned fb(float f) {
    union { float f; unsigned u; } c; c.f = f; return c.u;
}
static __device__ __forceinline__ float fu(unsigned u) {
    union { unsigned u; float f; } c; c.u = u; return c.f;
}

struct bfpair { short4v hi, lo; };

// Truncation split, pure C++: hi = trunc_bf16(v); lo = trunc_bf16(v - hi).
// v = hi + lo + err, |err| <= 2^-16 |v|.
static __device__ __forceinline__ bfpair split4(float4v v) {
    unsigned u0 = fb(v[0]), u1 = fb(v[1]), u2 = fb(v[2]), u3 = fb(v[3]);
    float l0 = v[0] - fu(u0 & 0xffff0000u);
    float l1 = v[1] - fu(u1 & 0xffff0000u);
    float l2 = v[2] - fu(u2 & 0xffff0000u);
    float l3 = v[3] - fu(u3 & 0xffff0000u);
    union { unsigned u[2]; short4v s; } H, L;
    H.u[0] = __builtin_amdgcn_perm(u1, u0, 0x07060302u);       // [hi(v0) | hi(v1)]
    H.u[1] = __builtin_amdgcn_perm(u3, u2, 0x07060302u);
    L.u[0] = __builtin_amdgcn_perm(fb(l1), fb(l0), 0x07060302u);
    L.u[1] = __builtin_amdgcn_perm(fb(l3), fb(l2), 0x07060302u);
    bfpair P; P.hi = H.s; P.lo = L.s; return P;
}

// hi-only truncation pack: 2 VALU per 4 values
static __device__ __forceinline__ short4v pack_hi4(float4v v) {
    union { unsigned u[2]; short4v s; } H;
    H.u[0] = __builtin_amdgcn_perm(fb(v[1]), fb(v[0]), 0x07060302u);
    H.u[1] = __builtin_amdgcn_perm(fb(v[3]), fb(v[2]), 0x07060302u);
    return H.s;
}

static __device__ __forceinline__ float sigmoid_f(float p) {
    return __builtin_amdgcn_rcpf(1.0f + __expf(-p));
}

__global__ __launch_bounds__(256, 7) void pcnet_kernel(
    const float* __restrict__ x,    // [B,16]
    const float* __restrict__ W1,   // [64,16]
    const float* __restrict__ b1,   // [64]
    const float* __restrict__ W2,   // [16,64]
    const float* __restrict__ b2,   // [16]
    const float* __restrict__ x1i,  // [B,64]
    const float* __restrict__ x2i,  // [B,16]
    float* __restrict__ out)        // [B,64] x1 then [B,16] x2
{
    const int tid  = blockIdx.x * 256 + threadIdx.x;
    const int wave = tid >> 6;
    const int lane = threadIdx.x & 63;
    const int g = lane >> 4;          // lane group 0..3
    const int q = lane & 15;          // 16x16 row/col index
    const int r = wave * 16 + q;      // batch row handled by this lane (ILP=1)

    // ---- W2 A-frags: A[q][4g+j] = W2[q][16c+4g+j], split hi/lo ----
    bfpair a_w2[4];
#pragma unroll
    for (int c = 0; c < 4; ++c) {
        float4v w = *(const float4v*)(W2 + q * 64 + 16 * c + 4 * g);
        a_w2[c] = split4(w);
    }
    const float4v b2f = *(const float4v*)(b2 + 4 * g);
    const float4v zero4 = {0.f, 0.f, 0.f, 0.f};

    // ---- M_hat FIRST so a_w2[*].lo dies before the t-loop (register peak) ----
    float4v Ma = zero4, Mb = zero4, Mc = zero4;
#pragma unroll
    for (int c = 0; c < 4; ++c) {
        Ma = MFMA16(a_w2[c].hi, a_w2[c].hi, Ma, 0, 0, 0);
        Mb = MFMA16(a_w2[c].hi, a_w2[c].lo, Mb, 0, 0, 0);
        Mc = MFMA16(a_w2[c].lo, a_w2[c].hi, Mc, 0, 0, 0);
    }
    short4v mfr = pack_hi4(0.2f * ((Ma + Mb) + Mc));

    // ---- x split ----
    bfpair bx = split4(*(const float4v*)(x + r * 16 + 4 * g));

    // ---- fused setup: per t-chunk compute mu1 (3-way split GEMM), fold x1c,
    //      accumulate p0 & c1 (hi-only W2: errors transient / <1e-3 after gain) ----
    float4v x1c[4];                    // lambda*x1_0 + (1-lambda)*mu1
    float4v pacc = b2f, cacc = zero4;  // p0 = W2@x1_0 + b2 ; c1 = W2@mu1
#pragma unroll
    for (int t = 0; t < 4; ++t) {
        float4v aw = *(const float4v*)(W1 + (16 * t + q) * 16 + 4 * g);
        bfpair a1 = split4(aw);
        float4v acc = *(const float4v*)(b1 + 16 * t + 4 * g);
        acc = MFMA16(a1.hi, bx.hi, acc, 0, 0, 0);
        acc = MFMA16(a1.hi, bx.lo, acc, 0, 0, 0);
        acc = MFMA16(a1.lo, bx.hi, acc, 0, 0, 0);
        float4v x10 = *(const float4v*)(x1i + r * 64 + 16 * t + 4 * g);
        float4v m;
#pragma unroll
        for (int j = 0; j < 4; ++j) m[j] = sigmoid_f(acc[j]);
        x1c[t] = LAMBDA * x10 + ONEMLAM * m;              // pk
        pacc = MFMA16(a_w2[t].hi, pack_hi4(x10), pacc, 0, 0, 0);
        cacc = MFMA16(a_w2[t].hi, pack_hi4(m),   cacc, 0, 0, 0);
    }
    float4v pv = pacc;
    float4v qv = 0.2f * (b2f + cacc);                     // pk

    // ---- state: p (16-dim projection), x2, S = sum 0.8^k d ----
    float4v x2v = *(const float4v*)(x2i + r * 16 + 4 * g);
    float4v Sv = zero4;

    // ---- 30 steps in 16-dim space; loop-live ~46 VGPR, 7-8 waves/SIMD ----
#pragma unroll 1
    for (int s = 0; s < NSTEPS; ++s) {
        float4v mu2;
#pragma unroll
        for (int j = 0; j < 4; ++j) mu2[j] = sigmoid_f(pv[j]);
        float4v e2 = x2v - mu2;                  // pk
        float4v mm = mu2 - mu2 * mu2;            // pk x2
        float4v dv = e2 * mm;                    // pk
        x2v = x2v - 0.2f * e2;                   // pk fma
        Sv  = 0.8f * Sv + dv;                    // pk fma
        float4v pn = 0.8f * pv + qv;             // pk fma
        pv = MFMA16(mfr, pack_hi4(dv), pn, 0, 0, 0);
    }

    // ---- epilogue: x1_N = x1c + 0.2*W2^T @ S ----
    short4v bs = pack_hi4(Sv);
#pragma unroll
    for (int t = 0; t < 4; ++t) {
        float4v e;
        e[0] = 0.2f * W2[(4 * g + 0) * 64 + 16 * t + q];
        e[1] = 0.2f * W2[(4 * g + 1) * 64 + 16 * t + q];
        e[2] = 0.2f * W2[(4 * g + 2) * 64 + 16 * t + q];
        e[3] = 0.2f * W2[(4 * g + 3) * 64 + 16 * t + q];
        bfpair a_ep = split4(e);
        float4v acc = x1c[t];
        acc = MFMA16(a_ep.hi, bs, acc, 0, 0, 0);
        acc = MFMA16(a_ep.lo, bs, acc, 0, 0, 0);
        *(float4v*)(out + r * 64 + 16 * t + 4 * g) = acc;
    }
    *(float4v*)(out + (size_t)NB * 64 + r * 16 + 4 * g) = x2v;
}

extern "C" void kernel_launch(void* const* d_in, const int* in_sizes, int n_in,
                              void* d_out, int out_size, void* d_ws, size_t ws_size,
                              hipStream_t stream) {
    const float* x   = (const float*)d_in[0];
    const float* W1  = (const float*)d_in[1];
    const float* b1  = (const float*)d_in[2];
    const float* W2  = (const float*)d_in[3];
    const float* b2  = (const float*)d_in[4];
    const float* x1i = (const float*)d_in[5];
    const float* x2i = (const float*)d_in[6];
    float* out = (float*)d_out;

    dim3 grid(NB / 64);   // 16 rows per wave (ILP=1), 4 waves per block -> 8192 waves
    dim3 block(256);
    pcnet_kernel<<<grid, block, 0, stream>>>(x, W1, b1, W2, b2, x1i, x2i, out);
}

// Round 13
// 37.778 us; speedup vs baseline: 1.1303x; 1.1303x over previous
//
#include <hip/hip_runtime.h>

#define NB 131072
#define NSTEPS 30
// 0.8^30 and 1-0.8^30
#define LAMBDA  1.2379400392853803e-3f
#define ONEMLAM 0.9987620599607146f

typedef float  float4v __attribute__((ext_vector_type(4)));
typedef short  short4v __attribute__((ext_vector_type(4)));

#define MFMA16 __builtin_amdgcn_mfma_f32_16x16x16bf16_1k

static __device__ __forceinline__ unsigned fb(float f) {
    union { float f; unsigned u; } c; c.f = f; return c.u;
}
static __device__ __forceinline__ float fu(unsigned u) {
    union { unsigned u; float f; } c; c.u = u; return c.f;
}

struct bfpair { short4v hi, lo; };

// Truncation split, pure C++: hi = trunc_bf16(v); lo = trunc_bf16(v - hi).
// v = hi + lo + err, |err| <= 2^-16 |v|.
static __device__ __forceinline__ bfpair split4(float4v v) {
    unsigned u0 = fb(v[0]), u1 = fb(v[1]), u2 = fb(v[2]), u3 = fb(v[3]);
    float l0 = v[0] - fu(u0 & 0xffff0000u);
    float l1 = v[1] - fu(u1 & 0xffff0000u);
    float l2 = v[2] - fu(u2 & 0xffff0000u);
    float l3 = v[3] - fu(u3 & 0xffff0000u);
    union { unsigned u[2]; short4v s; } H, L;
    H.u[0] = __builtin_amdgcn_perm(u1, u0, 0x07060302u);       // [hi(v0) | hi(v1)]
    H.u[1] = __builtin_amdgcn_perm(u3, u2, 0x07060302u);
    L.u[0] = __builtin_amdgcn_perm(fb(l1), fb(l0), 0x07060302u);
    L.u[1] = __builtin_amdgcn_perm(fb(l3), fb(l2), 0x07060302u);
    bfpair P; P.hi = H.s; P.lo = L.s; return P;
}

// hi-only truncation pack: 2 VALU per 4 values
static __device__ __forceinline__ short4v pack_hi4(float4v v) {
    union { unsigned u[2]; short4v s; } H;
    H.u[0] = __builtin_amdgcn_perm(fb(v[1]), fb(v[0]), 0x07060302u);
    H.u[1] = __builtin_amdgcn_perm(fb(v[3]), fb(v[2]), 0x07060302u);
    return H.s;
}

static __device__ __forceinline__ float sigmoid_f(float p) {
    return __builtin_amdgcn_rcpf(1.0f + __expf(-p));
}

__global__ __launch_bounds__(256, 3) void pcnet_kernel(
    const float* __restrict__ x,    // [B,16]
    const float* __restrict__ W1,   // [64,16]
    const float* __restrict__ b1,   // [64]
    const float* __restrict__ W2,   // [16,64]
    const float* __restrict__ b2,   // [16]
    const float* __restrict__ x1i,  // [B,64]
    const float* __restrict__ x2i,  // [B,16]
    float* __restrict__ out)        // [B,64] x1 then [B,16] x2
{
    const int tid  = blockIdx.x * 256 + threadIdx.x;
    const int wave = tid >> 6;
    const int lane = threadIdx.x & 63;
    const int g = lane >> 4;          // lane group 0..3
    const int q = lane & 15;          // 16x16 row/col index
    // two independent row groups per wave (ILP=2)
    int rr[2];
    rr[0] = wave * 32 + q;
    rr[1] = rr[0] + 16;

    // ================= PHASE 1: issue ALL global loads back-to-back =========
    float4v w2raw[4], awraw[4], binitraw[4], x1raw[2][4], xraw[2], x2raw[2];
#pragma unroll
    for (int c = 0; c < 4; ++c)
        w2raw[c] = *(const float4v*)(W2 + q * 64 + 16 * c + 4 * g);
#pragma unroll
    for (int t = 0; t < 4; ++t)
        awraw[t] = *(const float4v*)(W1 + (16 * t + q) * 16 + 4 * g);
#pragma unroll
    for (int t = 0; t < 4; ++t)
        binitraw[t] = *(const float4v*)(b1 + 16 * t + 4 * g);
#pragma unroll
    for (int i = 0; i < 2; ++i) {
#pragma unroll
        for (int t = 0; t < 4; ++t)
            x1raw[i][t] = *(const float4v*)(x1i + rr[i] * 64 + 16 * t + 4 * g);
        xraw[i]  = *(const float4v*)(x + rr[i] * 16 + 4 * g);
        x2raw[i] = *(const float4v*)(x2i + rr[i] * 16 + 4 * g);
    }
    const float4v b2f = *(const float4v*)(b2 + 4 * g);
    const float4v zero4 = {0.f, 0.f, 0.f, 0.f};

    // ================= PHASE 2: compute on registered values ================
    // W2 A-frags: A[q][4g+j] = W2[q][16c+4g+j], split hi/lo
    bfpair a_w2[4];
#pragma unroll
    for (int c = 0; c < 4; ++c) a_w2[c] = split4(w2raw[c]);

    // M_hat = 0.2*(W2 @ W2^T) — pure MFMA, overlaps outstanding loads
    float4v Ma = zero4, Mb = zero4, Mc = zero4;
#pragma unroll
    for (int c = 0; c < 4; ++c) {
        Ma = MFMA16(a_w2[c].hi, a_w2[c].hi, Ma, 0, 0, 0);
        Mb = MFMA16(a_w2[c].hi, a_w2[c].lo, Mb, 0, 0, 0);
        Mc = MFMA16(a_w2[c].lo, a_w2[c].hi, Mc, 0, 0, 0);
    }
    short4v mfr = pack_hi4(0.2f * ((Ma + Mb) + Mc));

    // x splits
    bfpair bx[2];
#pragma unroll
    for (int i = 0; i < 2; ++i) bx[i] = split4(xraw[i]);

    // fused setup: per t-chunk mu1 (3-way split GEMM), fold x1c, p0 & c1 (hi-only)
    float4v x1c[2][4];                 // lambda*x1_0 + (1-lambda)*mu1
    float4v pacc[2], cacc[2];          // p0 = W2@x1_0 + b2 ; c1 = W2@mu1
#pragma unroll
    for (int i = 0; i < 2; ++i) { pacc[i] = b2f; cacc[i] = zero4; }
#pragma unroll
    for (int t = 0; t < 4; ++t) {
        bfpair a1 = split4(awraw[t]);                     // shared across groups
#pragma unroll
        for (int i = 0; i < 2; ++i) {
            float4v acc = binitraw[t];
            acc = MFMA16(a1.hi, bx[i].hi, acc, 0, 0, 0);
            acc = MFMA16(a1.hi, bx[i].lo, acc, 0, 0, 0);
            acc = MFMA16(a1.lo, bx[i].hi, acc, 0, 0, 0);
            float4v m;
#pragma unroll
            for (int j = 0; j < 4; ++j) m[j] = sigmoid_f(acc[j]);
            x1c[i][t] = LAMBDA * x1raw[i][t] + ONEMLAM * m;   // pk
            pacc[i] = MFMA16(a_w2[t].hi, pack_hi4(x1raw[i][t]), pacc[i], 0, 0, 0);
            cacc[i] = MFMA16(a_w2[t].hi, pack_hi4(m),           cacc[i], 0, 0, 0);
        }
    }
    float4v pv[2], qv[2];
#pragma unroll
    for (int i = 0; i < 2; ++i) {
        pv[i] = pacc[i];
        qv[i] = 0.2f * (b2f + cacc[i]);                   // pk
    }

    // state: p (16-dim projection), x2, S = sum 0.8^k d
    float4v x2v[2], Sv[2];
#pragma unroll
    for (int i = 0; i < 2; ++i) { x2v[i] = x2raw[i]; Sv[i] = zero4; }

    // ---- 30 steps, two independent 16-dim chains, vector (pk) elementwise ----
#pragma unroll 1
    for (int s = 0; s < NSTEPS; ++s) {
#pragma unroll
        for (int i = 0; i < 2; ++i) {
            float4v mu2;
#pragma unroll
            for (int j = 0; j < 4; ++j) mu2[j] = sigmoid_f(pv[i][j]);
            float4v e2 = x2v[i] - mu2;                   // pk
            float4v mm = mu2 - mu2 * mu2;                // pk x2
            float4v dv = e2 * mm;                        // pk
            x2v[i] = x2v[i] - 0.2f * e2;                 // pk fma
            Sv[i]  = 0.8f * Sv[i] + dv;                  // pk fma
            float4v pn = 0.8f * pv[i] + qv[i];           // pk fma
            pv[i] = MFMA16(mfr, pack_hi4(dv), pn, 0, 0, 0);
        }
    }

    // ---- epilogue: x1_N = x1c + 0.2*W2^T @ S ; A-frag shared across groups ----
    short4v bs[2];
#pragma unroll
    for (int i = 0; i < 2; ++i) bs[i] = pack_hi4(Sv[i]);
#pragma unroll
    for (int t = 0; t < 4; ++t) {
        float4v e;
        e[0] = 0.2f * W2[(4 * g + 0) * 64 + 16 * t + q];
        e[1] = 0.2f * W2[(4 * g + 1) * 64 + 16 * t + q];
        e[2] = 0.2f * W2[(4 * g + 2) * 64 + 16 * t + q];
        e[3] = 0.2f * W2[(4 * g + 3) * 64 + 16 * t + q];
        bfpair a_ep = split4(e);
#pragma unroll
        for (int i = 0; i < 2; ++i) {
            float4v acc = x1c[i][t];
            acc = MFMA16(a_ep.hi, bs[i], acc, 0, 0, 0);
            acc = MFMA16(a_ep.lo, bs[i], acc, 0, 0, 0);
            *(float4v*)(out + rr[i] * 64 + 16 * t + 4 * g) = acc;
        }
    }
#pragma unroll
    for (int i = 0; i < 2; ++i)
        *(float4v*)(out + (size_t)NB * 64 + rr[i] * 16 + 4 * g) = x2v[i];
}

extern "C" void kernel_launch(void* const* d_in, const int* in_sizes, int n_in,
                              void* d_out, int out_size, void* d_ws, size_t ws_size,
                              hipStream_t stream) {
    const float* x   = (const float*)d_in[0];
    const float* W1  = (const float*)d_in[1];
    const float* b1  = (const float*)d_in[2];
    const float* W2  = (const float*)d_in[3];
    const float* b2  = (const float*)d_in[4];
    const float* x1i = (const float*)d_in[5];
    const float* x2i = (const float*)d_in[6];
    float* out = (float*)d_out;

    dim3 grid(NB / 128);   // 32 rows per wave (ILP=2), 4 waves per block
    dim3 block(256);
    pcnet_kernel<<<grid, block, 0, stream>>>(x, W1, b1, W2, b2, x1i, x2i, out);
}

// Round 14
// 37.526 us; speedup vs baseline: 1.1379x; 1.0067x over previous
//
#include <hip/hip_runtime.h>

#define NB 131072
#define NSTEPS 30
// 0.8^30 and 1-0.8^30
#define LAMBDA  1.2379400392853803e-3f
#define ONEMLAM 0.9987620599607146f

typedef float  float4v __attribute__((ext_vector_type(4)));
typedef short  short4v __attribute__((ext_vector_type(4)));

#define MFMA16 __builtin_amdgcn_mfma_f32_16x16x16bf16_1k

static __device__ __forceinline__ unsigned fb(float f) {
    union { float f; unsigned u; } c; c.f = f; return c.u;
}
static __device__ __forceinline__ float fu(unsigned u) {
    union { unsigned u; float f; } c; c.u = u; return c.f;
}

struct bfpair { short4v hi, lo; };

// Truncation split, pure C++: hi = trunc_bf16(v); lo = trunc_bf16(v - hi).
// v = hi + lo + err, |err| <= 2^-16 |v|.
static __device__ __forceinline__ bfpair split4(float4v v) {
    unsigned u0 = fb(v[0]), u1 = fb(v[1]), u2 = fb(v[2]), u3 = fb(v[3]);
    float l0 = v[0] - fu(u0 & 0xffff0000u);
    float l1 = v[1] - fu(u1 & 0xffff0000u);
    float l2 = v[2] - fu(u2 & 0xffff0000u);
    float l3 = v[3] - fu(u3 & 0xffff0000u);
    union { unsigned u[2]; short4v s; } H, L;
    H.u[0] = __builtin_amdgcn_perm(u1, u0, 0x07060302u);       // [hi(v0) | hi(v1)]
    H.u[1] = __builtin_amdgcn_perm(u3, u2, 0x07060302u);
    L.u[0] = __builtin_amdgcn_perm(fb(l1), fb(l0), 0x07060302u);
    L.u[1] = __builtin_amdgcn_perm(fb(l3), fb(l2), 0x07060302u);
    bfpair P; P.hi = H.s; P.lo = L.s; return P;
}

// hi-only truncation pack: 2 VALU per 4 values
static __device__ __forceinline__ short4v pack_hi4(float4v v) {
    union { unsigned u[2]; short4v s; } H;
    H.u[0] = __builtin_amdgcn_perm(fb(v[1]), fb(v[0]), 0x07060302u);
    H.u[1] = __builtin_amdgcn_perm(fb(v[3]), fb(v[2]), 0x07060302u);
    return H.s;
}

static __device__ __forceinline__ float sigmoid_f(float p) {
    return __builtin_amdgcn_rcpf(1.0f + __expf(-p));
}

__global__ __launch_bounds__(256, 2) void pcnet_kernel(
    const float* __restrict__ x,    // [B,16]
    const float* __restrict__ W1,   // [64,16]
    const float* __restrict__ b1,   // [64]
    const float* __restrict__ W2,   // [16,64]
    const float* __restrict__ b2,   // [16]
    const float* __restrict__ x1i,  // [B,64]
    const float* __restrict__ x2i,  // [B,16]
    float* __restrict__ out)        // [B,64] x1 then [B,16] x2
{
    // Occupancy throttle: 60 KB LDS -> 2 blocks/CU resident; grid is 4
    // blocks/CU of work -> 2 rounds -> round-2 loads overlap round-1 compute.
    __shared__ float lds_throttle[15360];
    ((volatile float*)lds_throttle)[threadIdx.x] = 0.0f;   // keep allocation live

    const int tid  = blockIdx.x * 256 + threadIdx.x;
    const int wave = tid >> 6;
    const int lane = threadIdx.x & 63;
    const int g = lane >> 4;          // lane group 0..3
    const int q = lane & 15;          // 16x16 row/col index
    // two independent row groups per wave (ILP=2)
    int rr[2];
    rr[0] = wave * 32 + q;
    rr[1] = rr[0] + 16;

    // ---- W2 A-frags (shared): A[q][4g+j] = W2[q][16c+4g+j], split hi/lo ----
    bfpair a_w2[4];
#pragma unroll
    for (int c = 0; c < 4; ++c) {
        float4v w = *(const float4v*)(W2 + q * 64 + 16 * c + 4 * g);
        a_w2[c] = split4(w);
    }
    const float4v b2f = *(const float4v*)(b2 + 4 * g);
    const float4v zero4 = {0.f, 0.f, 0.f, 0.f};

    // ---- x per group ----
    bfpair bx[2];
#pragma unroll
    for (int i = 0; i < 2; ++i)
        bx[i] = split4(*(const float4v*)(x + rr[i] * 16 + 4 * g));

    // ---- fused setup: per t-chunk compute mu1 (3-way split GEMM), fold x1c,
    //      accumulate p0 & c1 (hi-only: errors transient / <1e-3 after gain) ----
    float4v x1c[2][4];                 // lambda*x1_0 + (1-lambda)*mu1
    float4v pacc[2], cacc[2];          // p0 = W2@x1_0 + b2 ; c1 = W2@mu1
#pragma unroll
    for (int i = 0; i < 2; ++i) { pacc[i] = b2f; cacc[i] = zero4; }
#pragma unroll
    for (int t = 0; t < 4; ++t) {
        float4v aw = *(const float4v*)(W1 + (16 * t + q) * 16 + 4 * g);
        bfpair a1 = split4(aw);                           // shared across groups
        float4v binit = *(const float4v*)(b1 + 16 * t + 4 * g);
#pragma unroll
        for (int i = 0; i < 2; ++i) {
            float4v acc = binit;
            acc = MFMA16(a1.hi, bx[i].hi, acc, 0, 0, 0);
            acc = MFMA16(a1.hi, bx[i].lo, acc, 0, 0, 0);
            acc = MFMA16(a1.lo, bx[i].hi, acc, 0, 0, 0);
            float4v x10 = *(const float4v*)(x1i + rr[i] * 64 + 16 * t + 4 * g);
            float4v m;
#pragma unroll
            for (int j = 0; j < 4; ++j) m[j] = sigmoid_f(acc[j]);
            x1c[i][t] = LAMBDA * x10 + ONEMLAM * m;       // pk
            pacc[i] = MFMA16(a_w2[t].hi, pack_hi4(x10), pacc[i], 0, 0, 0);
            cacc[i] = MFMA16(a_w2[t].hi, pack_hi4(m),   cacc[i], 0, 0, 0);
        }
    }
    float4v pv[2], qv[2];
#pragma unroll
    for (int i = 0; i < 2; ++i) {
        pv[i] = pacc[i];
        qv[i] = 0.2f * (b2f + cacc[i]);                   // pk
    }

    // ---- M_hat = 0.2*(W2 @ W2^T), hi-only frag (symmetric: C-layout == A-frag) ----
    float4v Ma = zero4, Mb = zero4, Mc = zero4;
#pragma unroll
    for (int c = 0; c < 4; ++c) {
        Ma = MFMA16(a_w2[c].hi, a_w2[c].hi, Ma, 0, 0, 0);
        Mb = MFMA16(a_w2[c].hi, a_w2[c].lo, Mb, 0, 0, 0);
        Mc = MFMA16(a_w2[c].lo, a_w2[c].hi, Mc, 0, 0, 0);
    }
    short4v mfr = pack_hi4(0.2f * ((Ma + Mb) + Mc));

    // ---- state: p (16-dim projection), x2, S = sum 0.8^k d ----
    float4v x2v[2], Sv[2];
#pragma unroll
    for (int i = 0; i < 2; ++i) {
        x2v[i] = *(const float4v*)(x2i + rr[i] * 16 + 4 * g);
        Sv[i] = zero4;
    }

    // ---- 30 steps, two independent 16-dim chains, vector (pk) elementwise ----
#pragma unroll 1
    for (int s = 0; s < NSTEPS; ++s) {
#pragma unroll
        for (int i = 0; i < 2; ++i) {
            float4v mu2;
#pragma unroll
            for (int j = 0; j < 4; ++j) mu2[j] = sigmoid_f(pv[i][j]);
            float4v e2 = x2v[i] - mu2;                   // pk
            float4v mm = mu2 - mu2 * mu2;                // pk x2
            float4v dv = e2 * mm;                        // pk
            x2v[i] = x2v[i] - 0.2f * e2;                 // pk fma
            Sv[i]  = 0.8f * Sv[i] + dv;                  // pk fma
            float4v pn = 0.8f * pv[i] + qv[i];           // pk fma
            pv[i] = MFMA16(mfr, pack_hi4(dv), pn, 0, 0, 0);
        }
    }

    // ---- epilogue: x1_N = x1c + 0.2*W2^T @ S ; A-frag shared across groups ----
    short4v bs[2];
#pragma unroll
    for (int i = 0; i < 2; ++i) bs[i] = pack_hi4(Sv[i]);
#pragma unroll
    for (int t = 0; t < 4; ++t) {
        float4v e;
        e[0] = 0.2f * W2[(4 * g + 0) * 64 + 16 * t + q];
        e[1] = 0.2f * W2[(4 * g + 1) * 64 + 16 * t + q];
        e[2] = 0.2f * W2[(4 * g + 2) * 64 + 16 * t + q];
        e[3] = 0.2f * W2[(4 * g + 3) * 64 + 16 * t + q];
        bfpair a_ep = split4(e);
#pragma unroll
        for (int i = 0; i < 2; ++i) {
            float4v acc = x1c[i][t];
            acc = MFMA16(a_ep.hi, bs[i], acc, 0, 0, 0);
            acc = MFMA16(a_ep.lo, bs[i], acc, 0, 0, 0);
            *(float4v*)(out + rr[i] * 64 + 16 * t + 4 * g) = acc;
        }
    }
#pragma unroll
    for (int i = 0; i < 2; ++i)
        *(float4v*)(out + (size_t)NB * 64 + rr[i] * 16 + 4 * g) = x2v[i];
}

extern "C" void kernel_launch(void* const* d_in, const int* in_sizes, int n_in,
                              void* d_out, int out_size, void* d_ws, size_t ws_size,
                              hipStream_t stream) {
    const float* x   = (const float*)d_in[0];
    const float* W1  = (const float*)d_in[1];
    const float* b1  = (const float*)d_in[2];
    const float* W2  = (const float*)d_in[3];
    const float* b2  = (const float*)d_in[4];
    const float* x1i = (const float*)d_in[5];
    const float* x2i = (const float*)d_in[6];
    float* out = (float*)d_out;

    dim3 grid(NB / 128);   // 32 rows per wave (ILP=2), 4 waves per block
    dim3 block(256);
    pcnet_kernel<<<grid, block, 0, stream>>>(x, W1, b1, W2, b2, x1i, x2i, out);
}

// Round 15
// 35.174 us; speedup vs baseline: 1.2140x; 1.0669x over previous
//
#include <hip/hip_runtime.h>

#define NB 131072
#define NSTEPS 30
// 0.8^30 and 1-0.8^30
#define LAMBDA  1.2379400392853803e-3f
#define ONEMLAM 0.9987620599607146f
// -log2(e), -0.2*log2(e)
#define NLOG2E  (-1.4426950408889634f)
#define NLOG2E5 (-0.28853900817779268f)

typedef float  float4v __attribute__((ext_vector_type(4)));
typedef short  short4v __attribute__((ext_vector_type(4)));

#define MFMA16 __builtin_amdgcn_mfma_f32_16x16x16bf16_1k

static __device__ __forceinline__ unsigned fb(float f) {
    union { float f; unsigned u; } c; c.f = f; return c.u;
}
static __device__ __forceinline__ float fu(unsigned u) {
    union { unsigned u; float f; } c; c.u = u; return c.f;
}

struct bfpair { short4v hi, lo; };

// Truncation split, pure C++: hi = trunc_bf16(v); lo = trunc_bf16(v - hi).
// v = hi + lo + err, |err| <= 2^-16 |v|.
static __device__ __forceinline__ bfpair split4(float4v v) {
    unsigned u0 = fb(v[0]), u1 = fb(v[1]), u2 = fb(v[2]), u3 = fb(v[3]);
    float l0 = v[0] - fu(u0 & 0xffff0000u);
    float l1 = v[1] - fu(u1 & 0xffff0000u);
    float l2 = v[2] - fu(u2 & 0xffff0000u);
    float l3 = v[3] - fu(u3 & 0xffff0000u);
    union { unsigned u[2]; short4v s; } H, L;
    H.u[0] = __builtin_amdgcn_perm(u1, u0, 0x07060302u);       // [hi(v0) | hi(v1)]
    H.u[1] = __builtin_amdgcn_perm(u3, u2, 0x07060302u);
    L.u[0] = __builtin_amdgcn_perm(fb(l1), fb(l0), 0x07060302u);
    L.u[1] = __builtin_amdgcn_perm(fb(l3), fb(l2), 0x07060302u);
    bfpair P; P.hi = H.s; P.lo = L.s; return P;
}

// hi-only truncation pack: 2 VALU per 4 values
static __device__ __forceinline__ short4v pack_hi4(float4v v) {
    union { unsigned u[2]; short4v s; } H;
    H.u[0] = __builtin_amdgcn_perm(fb(v[1]), fb(v[0]), 0x07060302u);
    H.u[1] = __builtin_amdgcn_perm(fb(v[3]), fb(v[2]), 0x07060302u);
    return H.s;
}

static __device__ __forceinline__ float sigmoid_f(float p) {
    return __builtin_amdgcn_rcpf(1.0f + __expf(-p));
}

__global__ __launch_bounds__(256, 3) void pcnet_kernel(
    const float* __restrict__ x,    // [B,16]
    const float* __restrict__ W1,   // [64,16]
    const float* __restrict__ b1,   // [64]
    const float* __restrict__ W2,   // [16,64]
    const float* __restrict__ b2,   // [16]
    const float* __restrict__ x1i,  // [B,64]
    const float* __restrict__ x2i,  // [B,16]
    float* __restrict__ out)        // [B,64] x1 then [B,16] x2
{
    const int tid  = blockIdx.x * 256 + threadIdx.x;
    const int wave = tid >> 6;
    const int lane = threadIdx.x & 63;
    const int g = lane >> 4;          // lane group 0..3
    const int q = lane & 15;          // 16x16 row/col index
    // two independent row groups per wave (ILP=2)
    int rr[2];
    rr[0] = wave * 32 + q;
    rr[1] = rr[0] + 16;

    // ---- W2 A-frags (shared): A[q][4g+j] = W2[q][16c+4g+j], split hi/lo ----
    bfpair a_w2[4];
#pragma unroll
    for (int c = 0; c < 4; ++c) {
        float4v w = *(const float4v*)(W2 + q * 64 + 16 * c + 4 * g);
        a_w2[c] = split4(w);
    }
    const float4v b2f = *(const float4v*)(b2 + 4 * g);
    const float4v zero4 = {0.f, 0.f, 0.f, 0.f};

    // ---- x per group ----
    bfpair bx[2];
#pragma unroll
    for (int i = 0; i < 2; ++i)
        bx[i] = split4(*(const float4v*)(x + rr[i] * 16 + 4 * g));

    // ---- fused setup: per t-chunk compute mu1 (3-way split GEMM), fold x1c,
    //      accumulate p0 & c1 (hi-only: errors transient / <1e-3 after gain) ----
    float4v x1c[2][4];                 // lambda*x1_0 + (1-lambda)*mu1
    float4v pacc[2], cacc[2];          // p0 = W2@x1_0 + b2 ; c1 = W2@mu1
#pragma unroll
    for (int i = 0; i < 2; ++i) { pacc[i] = b2f; cacc[i] = zero4; }
#pragma unroll
    for (int t = 0; t < 4; ++t) {
        float4v aw = *(const float4v*)(W1 + (16 * t + q) * 16 + 4 * g);
        bfpair a1 = split4(aw);                           // shared across groups
        float4v binit = *(const float4v*)(b1 + 16 * t + 4 * g);
#pragma unroll
        for (int i = 0; i < 2; ++i) {
            float4v acc = binit;
            acc = MFMA16(a1.hi, bx[i].hi, acc, 0, 0, 0);
            acc = MFMA16(a1.hi, bx[i].lo, acc, 0, 0, 0);
            acc = MFMA16(a1.lo, bx[i].hi, acc, 0, 0, 0);
            float4v x10 = *(const float4v*)(x1i + rr[i] * 64 + 16 * t + 4 * g);
            float4v m;
#pragma unroll
            for (int j = 0; j < 4; ++j) m[j] = sigmoid_f(acc[j]);
            x1c[i][t] = LAMBDA * x10 + ONEMLAM * m;       // pk
            pacc[i] = MFMA16(a_w2[t].hi, pack_hi4(x10), pacc[i], 0, 0, 0);
            cacc[i] = MFMA16(a_w2[t].hi, pack_hi4(m),   cacc[i], 0, 0, 0);
        }
    }
    // p-tilde space: ptv = -log2e * p ; qtv = -0.2*log2e * (b2 + c1)
    float4v pv[2], qv[2];
#pragma unroll
    for (int i = 0; i < 2; ++i) {
        pv[i] = NLOG2E  * pacc[i];                        // pk
        qv[i] = NLOG2E5 * (b2f + cacc[i]);                // pk
    }

    // ---- M_tilde = -0.2*log2e*(W2 @ W2^T), hi-only frag (symmetric) ----
    float4v Ma = zero4, Mb = zero4, Mc = zero4;
#pragma unroll
    for (int c = 0; c < 4; ++c) {
        Ma = MFMA16(a_w2[c].hi, a_w2[c].hi, Ma, 0, 0, 0);
        Mb = MFMA16(a_w2[c].hi, a_w2[c].lo, Mb, 0, 0, 0);
        Mc = MFMA16(a_w2[c].lo, a_w2[c].hi, Mc, 0, 0, 0);
    }
    short4v mfr = pack_hi4(NLOG2E5 * ((Ma + Mb) + Mc));

    // ---- epilogue A-frag (hi-only), loaded & packed BEFORE the loop so the
    //      strided W2-column gather flows under the 30-step compute ----
    short4v a_ep[4];
#pragma unroll
    for (int t = 0; t < 4; ++t) {
        float4v e;
        e[0] = 0.2f * W2[(4 * g + 0) * 64 + 16 * t + q];
        e[1] = 0.2f * W2[(4 * g + 1) * 64 + 16 * t + q];
        e[2] = 0.2f * W2[(4 * g + 2) * 64 + 16 * t + q];
        e[3] = 0.2f * W2[(4 * g + 3) * 64 + 16 * t + q];
        a_ep[t] = pack_hi4(e);
    }

    // ---- state: p-tilde (16-dim projection), x2, S = sum 0.8^k d ----
    float4v x2v[2], Sv[2];
#pragma unroll
    for (int i = 0; i < 2; ++i) {
        x2v[i] = *(const float4v*)(x2i + rr[i] * 16 + 4 * g);
        Sv[i] = zero4;
    }

    // ---- 30 steps; sigmoid = rcp(1+exp2(pt)), no argument multiply ----
#pragma unroll 1
    for (int s = 0; s < NSTEPS; ++s) {
#pragma unroll
        for (int i = 0; i < 2; ++i) {
            float4v mu2;
#pragma unroll
            for (int j = 0; j < 4; ++j) {
                float E = __builtin_amdgcn_exp2f(pv[i][j]);   // 2^(pt) = e^(-p)
                mu2[j] = __builtin_amdgcn_rcpf(1.0f + E);
            }
            float4v e2 = x2v[i] - mu2;                   // pk
            float4v mm = mu2 - mu2 * mu2;                // pk x2
            float4v dv = e2 * mm;                        // pk
            x2v[i] = x2v[i] - 0.2f * e2;                 // pk fma
            Sv[i]  = 0.8f * Sv[i] + dv;                  // pk fma
            float4v pn = 0.8f * pv[i] + qv[i];           // pk fma
            pv[i] = MFMA16(mfr, pack_hi4(dv), pn, 0, 0, 0);
        }
    }

    // ---- epilogue: x1_N = x1c + 0.2*W2^T @ S (hi-only, pre-packed frags) ----
    short4v bs[2];
#pragma unroll
    for (int i = 0; i < 2; ++i) bs[i] = pack_hi4(Sv[i]);
#pragma unroll
    for (int t = 0; t < 4; ++t) {
#pragma unroll
        for (int i = 0; i < 2; ++i) {
            float4v acc = x1c[i][t];
            acc = MFMA16(a_ep[t], bs[i], acc, 0, 0, 0);
            *(float4v*)(out + rr[i] * 64 + 16 * t + 4 * g) = acc;
        }
    }
#pragma unroll
    for (int i = 0; i < 2; ++i)
        *(float4v*)(out + (size_t)NB * 64 + rr[i] * 16 + 4 * g) = x2v[i];
}

extern "C" void kernel_launch(void* const* d_in, const int* in_sizes, int n_in,
                              void* d_out, int out_size, void* d_ws, size_t ws_size,
                              hipStream_t stream) {
    const float* x   = (const float*)d_in[0];
    const float* W1  = (const float*)d_in[1];
    const float* b1  = (const float*)d_in[2];
    const float* W2  = (const float*)d_in[3];
    const float* b2  = (const float*)d_in[4];
    const float* x1i = (const float*)d_in[5];
    const float* x2i = (const float*)d_in[6];
    float* out = (float*)d_out;

    dim3 grid(NB / 128);   // 32 rows per wave (ILP=2), 4 waves per block
    dim3 block(256);
    pcnet_kernel<<<grid, block, 0, stream>>>(x, W1, b1, W2, b2, x1i, x2i, out);
}